// Round 4
// baseline (476.188 us; speedup 1.0000x reference)
//
#include <hip/hip_runtime.h>
#include <hip/hip_bf16.h>
#include <cstdint>
#include <cstddef>

// Problem constants
#define HIDDEN 1024
#define NHEADS 16
#define HD     64
#define BATCH  4
#define SEQ    4096
#define MTOT   (BATCH*SEQ)   // 16384
#define EPSF   1e-3f

typedef unsigned short u16;
typedef unsigned int   u32;
typedef __bf16 bf16x8 __attribute__((ext_vector_type(8)));
typedef u16    u16x8  __attribute__((ext_vector_type(8)));
typedef float  f32x4  __attribute__((ext_vector_type(4)));
typedef u32    u32x4  __attribute__((ext_vector_type(4)));

// f32 -> bf16 (RNE) via the compiler-native scalar __bf16 type.
// (__hip_bfloat16/__hip_bfloat162 are non-trivially-copyable classes on this
// ROCm -> __builtin_bit_cast rejects them; __bf16 is a scalar and fine.)
__device__ inline u16 f2bf(float a) {
    __bf16 h = (__bf16)a;
    return __builtin_bit_cast(u16, h);
}
__device__ inline u32 pack2bf(float a, float b) {
    return (u32)f2bf(a) | ((u32)f2bf(b) << 16);
}
__device__ inline float bf2f(u16 x) {
    return __builtin_bit_cast(float, (u32)x << 16);
}
__device__ inline f32x4 mfma16(bf16x8 a, bf16x8 b, f32x4 c) {
    return __builtin_amdgcn_mfma_f32_16x16x32_bf16(a, b, c, 0, 0, 0);
}
// async global->LDS, 16B per lane; lptr must be wave-uniform; HW writes
// lptr + lane*16 (linear). Swizzle lives in the per-lane GLOBAL address
// (rule #21: both-sides-or-neither; LDS dest stays linear).
__device__ inline void gl_lds16(const void* g, void* l) {
    __builtin_amdgcn_global_load_lds(
        (const __attribute__((address_space(1))) void*)g,
        (__attribute__((address_space(3))) void*)l,
        16, 0, 0);
}

// ---------------------------------------------------------------------------
// Kernel 1: weight transpose+convert (Wt[c][d] bf16 = W[d][c] f32), plus
// zeroing of the kvsT/ks_sum accumulator region (ws is poisoned each launch).
// grid (16,16,4), 256 threads. z<3: one 64x64 transpose tile; z==3: zero.
// Original wshape (HIDDEN, HEADS, HEAD_DIM) row-major => W[d][c], c = n*64+h.
// ---------------------------------------------------------------------------
__global__ __launch_bounds__(256) void prep_kernel(
    const float* __restrict__ W0, const float* __restrict__ W1,
    const float* __restrict__ W2, u16* __restrict__ Wt,
    float* __restrict__ zero_base)
{
    const int t = threadIdx.x;
    if (blockIdx.z == 3) {
        const int base = (blockIdx.y * 16 + blockIdx.x) * 256 + t;
        const int total = 64*64*64 + 64*64;   // kvsT + ks_sum floats (contiguous)
        for (int idx = base; idx < total; idx += 65536) zero_base[idx] = 0.f;
        return;
    }
    const int z = blockIdx.z;
    const float* __restrict__ W = (z == 0) ? W0 : ((z == 1) ? W1 : W2);
    u16* __restrict__ Wz = Wt + (size_t)z * HIDDEN * HIDDEN;
    const int d0 = blockIdx.y * 64, c0 = blockIdx.x * 64;
    __shared__ u16 T[64 * 72];   // row stride 72 u16 to break bank alignment
    {
        const int r = t & 63, p = t >> 6;   // row d, 16-col part
        const float* src = W + (size_t)(d0 + r) * HIDDEN + c0 + p * 16;
        f32x4 x0 = *(const f32x4*)src,       x1 = *(const f32x4*)(src + 4);
        f32x4 x2 = *(const f32x4*)(src + 8), x3 = *(const f32x4*)(src + 12);
        u32x4 y0 = { pack2bf(x0[0],x0[1]), pack2bf(x0[2],x0[3]),
                     pack2bf(x1[0],x1[1]), pack2bf(x1[2],x1[3]) };
        u32x4 y1 = { pack2bf(x2[0],x2[1]), pack2bf(x2[2],x2[3]),
                     pack2bf(x3[0],x3[1]), pack2bf(x3[2],x3[3]) };
        *(u32x4*)((char*)T + (size_t)(r * 72 + p * 16) * 2)     = y0;
        *(u32x4*)((char*)T + (size_t)(r * 72 + p * 16 + 8) * 2) = y1;
    }
    __syncthreads();
    {
        const int c = t & 63, p = t >> 6;   // out row c, 16-d part
        u16 vals[16];
        #pragma unroll
        for (int i = 0; i < 16; ++i) vals[i] = T[(p * 16 + i) * 72 + c];
        u16* dst = Wz + (size_t)(c0 + c) * HIDDEN + d0 + p * 16;
        *(u16x8*)dst       = *(const u16x8*)&vals[0];
        *(u16x8*)(dst + 8) = *(const u16x8*)&vals[8];
    }
}

// ---------------------------------------------------------------------------
// Kernel 2: X f32 -> bf16 streaming convert. grid (1024, 3), grid-stride.
// 16B loads + 16B stores per thread-iter; pure HBM streaming (~290 MB).
// ---------------------------------------------------------------------------
__global__ __launch_bounds__(256) void conv_kernel(
    const float* __restrict__ X0, const float* __restrict__ X1,
    const float* __restrict__ X2, u16* __restrict__ D0,
    u16* __restrict__ D1, u16* __restrict__ D2)
{
    const int z = blockIdx.y;
    const float* __restrict__ X = (z == 0) ? X0 : ((z == 1) ? X1 : X2);
    u16* __restrict__ D = (z == 0) ? D0 : ((z == 1) ? D1 : D2);
    const int ngrp = MTOT * HIDDEN / 8;   // 2,097,152 groups of 8
    for (int i = blockIdx.x * 256 + threadIdx.x; i < ngrp; i += 262144) {
        const size_t off = (size_t)i * 8;
        f32x4 a = *(const f32x4*)(X + off);
        f32x4 b = *(const f32x4*)(X + off + 4);
        u32x4 p = { pack2bf(a[0],a[1]), pack2bf(a[2],a[3]),
                    pack2bf(b[0],b[1]), pack2bf(b[2],b[3]) };
        *(u32x4*)(D + off) = p;
    }
}

// ---------------------------------------------------------------------------
// Kernel 3: projection GEMM, m97 structure. P[16384][1024] bf16 =
// act(Xb bf16 @ Wt^T). Wt is [n][k] bf16 so both operands are k-contiguous.
// 128x128 tile, BK=64, 4 waves, 4x4 16x16x32 frags/wave.
// Staging: global_load_lds 16B/lane, linear LDS dest. Physical slot s of row
// r holds logical chunk s^(r&7) (XOR pre-applied to per-lane global source,
// since staging lane layout has r&7 == lane>>3, slot == lane&7). All ds_reads
// apply the same XOR => bank-conflict-free b128 fragment reads.
// XCD-aware bijective remap (nwg=1024, 1024%8==0): each XCD gets 16
// consecutive m-stripes x all 8 n-tiles => W (2 MB) stays L2-resident.
// ---------------------------------------------------------------------------
__global__ __launch_bounds__(256) void gemm_proj(
    const u16* __restrict__ Xb, const u16* __restrict__ W,
    u16* __restrict__ Pz, const int doact)
{
    const int lin = blockIdx.y * 8 + blockIdx.x;      // 0..1023
    const int swz = (lin & 7) * 128 + (lin >> 3);     // bijective
    const int m0 = (swz >> 3) * 128;
    const int n0 = (swz & 7) * 128;

    __shared__ u16 As[128 * 64];   // [row][slot] of 8 bf16
    __shared__ u16 Bs[128 * 64];

    const int t = threadIdx.x, lane = t & 63, wid = t >> 6;
    const int wr = (wid >> 1) * 64, wc = (wid & 1) * 64;
    const int l15 = lane & 15, l4 = lane >> 4;
    const int srow = lane >> 3;                  // row within 8-row group
    const int schunk = (lane & 7) ^ srow;        // pre-swizzled source chunk

    f32x4 acc[4][4];
    #pragma unroll
    for (int i = 0; i < 4; ++i)
        #pragma unroll
        for (int j = 0; j < 4; ++j) acc[i][j] = f32x4{0.f, 0.f, 0.f, 0.f};

    for (int kt = 0; kt < HIDDEN / 64; ++kt) {
        const int k0 = kt * 64;
        __syncthreads();   // all waves done reading LDS before async overwrite
        #pragma unroll
        for (int g = 0; g < 4; ++g) {
            const int rbase = wid * 32 + g * 8;
            const int r = rbase + srow;
            gl_lds16(Xb + (size_t)(m0 + r) * HIDDEN + k0 + schunk * 8,
                     &As[rbase * 64]);
            gl_lds16(W + (size_t)(n0 + r) * HIDDEN + k0 + schunk * 8,
                     &Bs[rbase * 64]);
        }
        __syncthreads();   // compiler drains vmcnt(0) before s_barrier
        #pragma unroll
        for (int ks = 0; ks < 2; ++ks) {
            bf16x8 af[4], bfr[4];
            #pragma unroll
            for (int mi = 0; mi < 4; ++mi) {
                const int r = wr + mi * 16 + l15;
                const int c = (ks * 4 + l4) ^ (r & 7);
                af[mi] = *(const bf16x8*)((const char*)As + (size_t)r * 128 + c * 16);
            }
            #pragma unroll
            for (int ni = 0; ni < 4; ++ni) {
                const int r = wc + ni * 16 + l15;
                const int c = (ks * 4 + l4) ^ (r & 7);
                bfr[ni] = *(const bf16x8*)((const char*)Bs + (size_t)r * 128 + c * 16);
            }
            #pragma unroll
            for (int mi = 0; mi < 4; ++mi)
                #pragma unroll
                for (int ni = 0; ni < 4; ++ni)
                    acc[mi][ni] = mfma16(af[mi], bfr[ni], acc[mi][ni]);
        }
    }
    #pragma unroll
    for (int mi = 0; mi < 4; ++mi) {
        #pragma unroll
        for (int ni = 0; ni < 4; ++ni) {
            const int mrow = m0 + wr + mi * 16 + l4 * 4;   // C row = 4*(l>>4)+reg
            const int ncol = n0 + wc + ni * 16 + l15;      // C col = lane&15
            #pragma unroll
            for (int r = 0; r < 4; ++r) {
                float v = acc[mi][ni][r];
                if (doact) v = fmaxf(v, 0.f) + EPSF;      // relu + eps (q,k)
                Pz[(size_t)(mrow + r) * HIDDEN + ncol] = f2bf(v);
            }
        }
    }
}

// ---------------------------------------------------------------------------
// Kernel 4: kvsT[bn][d][m] += sum_s k'[s,m]*v'[s,d]; ks_sum[bn][m] += sum_s k'.
// Vector outer-product in fp32, atomics across 16 s-chunks. grid (64,16).
// ---------------------------------------------------------------------------
__global__ __launch_bounds__(256) void kvs_kernel(
    const u16* __restrict__ Kp, const u16* __restrict__ Vp,
    float* __restrict__ kvsT, float* __restrict__ ks_sum)
{
    const int bn = blockIdx.x, sc = blockIdx.y;
    const int b = bn >> 4, n = bn & 15;
    __shared__ float Ks[64 * 64];
    __shared__ float Vs[64 * 64];
    const int t = threadIdx.x;
    const int tm = t & 15, td = t >> 4;
    float acc[4][4] = {};
    float ksa[4] = {0.f, 0.f, 0.f, 0.f};
    const size_t rowbase = ((size_t)b * SEQ + (size_t)sc * 256) * HIDDEN + n * 64;

    for (int st = 0; st < 4; ++st) {
        __syncthreads();
        #pragma unroll
        for (int i = 0; i < 2; ++i) {
            const int j = i * 256 + t;
            const int r = j >> 3, c = j & 7;
            const size_t off = rowbase + (size_t)(st * 64 + r) * HIDDEN + c * 8;
            u16x8 kk = *(const u16x8*)(Kp + off);
            u16x8 vv = *(const u16x8*)(Vp + off);
            f32x4 ka{bf2f(kk[0]), bf2f(kk[1]), bf2f(kk[2]), bf2f(kk[3])};
            f32x4 kb{bf2f(kk[4]), bf2f(kk[5]), bf2f(kk[6]), bf2f(kk[7])};
            f32x4 va{bf2f(vv[0]), bf2f(vv[1]), bf2f(vv[2]), bf2f(vv[3])};
            f32x4 vb{bf2f(vv[4]), bf2f(vv[5]), bf2f(vv[6]), bf2f(vv[7])};
            *(f32x4*)&Ks[r * 64 + c * 8]     = ka;
            *(f32x4*)&Ks[r * 64 + c * 8 + 4] = kb;
            *(f32x4*)&Vs[r * 64 + c * 8]     = va;
            *(f32x4*)&Vs[r * 64 + c * 8 + 4] = vb;
        }
        __syncthreads();
        for (int s = 0; s < 64; ++s) {
            const f32x4 kk = *(const f32x4*)&Ks[s * 64 + tm * 4];
            const f32x4 vv = *(const f32x4*)&Vs[s * 64 + td * 4];
            #pragma unroll
            for (int i = 0; i < 4; ++i) {
                ksa[i] += kk[i];
                #pragma unroll
                for (int j = 0; j < 4; ++j) acc[i][j] += kk[i] * vv[j];
            }
        }
    }
    float* kt_bn = kvsT + (size_t)bn * 64 * 64;
    #pragma unroll
    for (int j = 0; j < 4; ++j)
        #pragma unroll
        for (int i = 0; i < 4; ++i)
            atomicAdd(&kt_bn[(td * 4 + j) * 64 + tm * 4 + i], acc[i][j]);
    if (td == 0) {   // ksa identical across td for a given tm -> add once
        #pragma unroll
        for (int i = 0; i < 4; ++i)
            atomicAdd(&ks_sum[bn * 64 + tm * 4 + i], ksa[i]);
    }
}

// ---------------------------------------------------------------------------
// Kernel 5: out[b][s][n*64+d] = (q' @ kvs) / (q' . ks_sum). MFMA over m (=64).
// grid (64,16): (b,n) x 256-row s-chunk. A = q' (swizzled LDS), B = kvsT
// converted to bf16 (swizzled LDS); normalizer dot in fp32 per s-row.
// ---------------------------------------------------------------------------
__global__ __launch_bounds__(256) void out_kernel(
    const u16* __restrict__ Qp, const float* __restrict__ kvsT,
    const float* __restrict__ ks_sum, float* __restrict__ out)
{
    const int bn = blockIdx.x, sc = blockIdx.y;
    const int b = bn >> 4, n = bn & 15;
    __shared__ u16 Aq[256 * 64];
    __shared__ u16 Bk[64 * 64];
    __shared__ float ksl[64];
    __shared__ float nrm[256];
    const int t = threadIdx.x, lane = t & 63, wid = t >> 6;
    const int l15 = lane & 15, l4 = lane >> 4;
    const size_t qbase = ((size_t)b * SEQ + (size_t)sc * 256) * HIDDEN + n * 64;

    #pragma unroll
    for (int i = 0; i < 8; ++i) {
        const int j = i * 256 + t;
        const int r = j >> 3, c = j & 7;
        u16x8 q8 = *(const u16x8*)(Qp + qbase + (size_t)r * HIDDEN + c * 8);
        *(u16x8*)((char*)Aq + (size_t)r * 128 + ((c ^ (r & 7)) * 16)) = q8;
    }
    {
        const int d = t & 63, p = t >> 6;
        const float* src = kvsT + ((size_t)bn * 64 + d) * 64 + p * 16;
        f32x4 x0 = *(const f32x4*)src,        x1 = *(const f32x4*)(src + 4);
        f32x4 x2 = *(const f32x4*)(src + 8),  x3 = *(const f32x4*)(src + 12);
        u32x4 y0 = { pack2bf(x0[0],x0[1]), pack2bf(x0[2],x0[3]),
                     pack2bf(x1[0],x1[1]), pack2bf(x1[2],x1[3]) };
        u32x4 y1 = { pack2bf(x2[0],x2[1]), pack2bf(x2[2],x2[3]),
                     pack2bf(x3[0],x3[1]), pack2bf(x3[2],x3[3]) };
        *(u32x4*)((char*)Bk + (size_t)d * 128 + (((p * 2)     ^ (d & 7)) * 16)) = y0;
        *(u32x4*)((char*)Bk + (size_t)d * 128 + (((p * 2 + 1) ^ (d & 7)) * 16)) = y1;
    }
    if (t < 16) ((f32x4*)ksl)[t] = ((const f32x4*)(ks_sum + bn * 64))[t];
    __syncthreads();
    {   // normalizer for this thread's s-row (row t), fp32
        float s = 0.f;
        #pragma unroll
        for (int c = 0; c < 8; ++c) {
            u16x8 q8 = *(const u16x8*)((const char*)Aq + (size_t)t * 128 + ((c ^ (t & 7)) * 16));
            #pragma unroll
            for (int e = 0; e < 8; ++e) s += bf2f(q8[e]) * ksl[c * 8 + e];
        }
        nrm[t] = s;   // strictly positive: q' >= eps, ks_sum >= 4096*eps
    }
    __syncthreads();
    f32x4 acc[4][4];
    #pragma unroll
    for (int i = 0; i < 4; ++i)
        #pragma unroll
        for (int j = 0; j < 4; ++j) acc[i][j] = f32x4{0.f, 0.f, 0.f, 0.f};
    #pragma unroll
    for (int ks = 0; ks < 2; ++ks) {
        bf16x8 af[4], bfr[4];
        #pragma unroll
        for (int mi = 0; mi < 4; ++mi) {
            const int r = wid * 64 + mi * 16 + l15;
            const int c = (ks * 4 + l4) ^ (r & 7);
            af[mi] = *(const bf16x8*)((const char*)Aq + (size_t)r * 128 + c * 16);
        }
        #pragma unroll
        for (int ni = 0; ni < 4; ++ni) {
            const int rd = ni * 16 + l15;
            const int c = (ks * 4 + l4) ^ (rd & 7);
            bfr[ni] = *(const bf16x8*)((const char*)Bk + (size_t)rd * 128 + c * 16);
        }
        #pragma unroll
        for (int mi = 0; mi < 4; ++mi)
            #pragma unroll
            for (int ni = 0; ni < 4; ++ni)
                acc[mi][ni] = mfma16(af[mi], bfr[ni], acc[mi][ni]);
    }
    const size_t obase = (size_t)b * SEQ + (size_t)sc * 256;
    #pragma unroll
    for (int mi = 0; mi < 4; ++mi) {
        const int s0l = wid * 64 + mi * 16 + l4 * 4;
        const float rn0 = 1.f / nrm[s0l],     rn1 = 1.f / nrm[s0l + 1];
        const float rn2 = 1.f / nrm[s0l + 2], rn3 = 1.f / nrm[s0l + 3];
        #pragma unroll
        for (int ni = 0; ni < 4; ++ni) {
            const int d = ni * 16 + l15;
            float* op = out + (obase + s0l) * (size_t)HIDDEN + n * 64 + d;
            op[0 * HIDDEN] = acc[mi][ni][0] * rn0;
            op[1 * HIDDEN] = acc[mi][ni][1] * rn1;
            op[2 * HIDDEN] = acc[mi][ni][2] * rn2;
            op[3 * HIDDEN] = acc[mi][ni][3] * rn3;
        }
    }
}

// ---------------------------------------------------------------------------
// ws layout (bytes) — 4-slot rotation, total ~141.6 MB:
//   [0)          Wt bf16 [3][1024][1024]            6,291,456
//   slotA        Xb_q, later P_k                   33,554,432
//   slotB        Xb_k, later P_v                   33,554,432
//   slotC        Xb_v                              33,554,432
//   slotD        P_q                               33,554,432
//   kvsT f32 [64][64][64]                           1,048,576
//   ks_sum f32 [64][64]                                16,384
// total = 141,573,952
// Launch order (stream-serialized) makes slot reuse race-free:
//   conv: Xq->A, Xk->B, Xv->C
//   gemm0: A -> D (q', relu+eps)   gemm1: B -> A (k')   gemm2: C -> B (v')
// ---------------------------------------------------------------------------
extern "C" void kernel_launch(void* const* d_in, const int* in_sizes, int n_in,
                              void* d_out, int out_size, void* d_ws, size_t ws_size,
                              hipStream_t stream)
{
    const float* Xq = (const float*)d_in[0];
    const float* Xk = (const float*)d_in[1];
    const float* Xv = (const float*)d_in[2];
    const float* Wq = (const float*)d_in[3];
    const float* Wk = (const float*)d_in[4];
    const float* Wv = (const float*)d_in[5];
    float* out = (float*)d_out;

    char* w = (char*)d_ws;
    u16*   Wt    = (u16*)w;
    u16*   slotA = (u16*)(w + 6291456);
    u16*   slotB = (u16*)(w + 6291456 + 1 * 33554432);
    u16*   slotC = (u16*)(w + 6291456 + 2 * 33554432);
    u16*   slotD = (u16*)(w + 6291456 + 3 * 33554432);
    float* kvsT  = (float*)(w + 6291456 + 4 * 33554432);
    float* ks    = (float*)(w + 6291456 + 4 * 33554432 + 1048576);

    prep_kernel<<<dim3(16, 16, 4), 256, 0, stream>>>(Wq, Wk, Wv, Wt, kvsT);
    conv_kernel<<<dim3(1024, 3), 256, 0, stream>>>(Xq, Xk, Xv, slotA, slotB, slotC);
    gemm_proj<<<dim3(8, 128), 256, 0, stream>>>(slotA, Wt,                 slotD, 1);
    gemm_proj<<<dim3(8, 128), 256, 0, stream>>>(slotB, Wt + 1048576,       slotA, 1);
    gemm_proj<<<dim3(8, 128), 256, 0, stream>>>(slotC, Wt + 2 * 1048576,   slotB, 0);
    kvs_kernel<<<dim3(64, 16), 256, 0, stream>>>(slotA, slotB, kvsT, ks);
    out_kernel<<<dim3(64, 16), 256, 0, stream>>>(slotD, kvsT, ks, out);
}

// Round 8
// 465.153 us; speedup vs baseline: 1.0237x; 1.0237x over previous
//
#include <hip/hip_runtime.h>
#include <hip/hip_bf16.h>
#include <cstdint>
#include <cstddef>

// Problem constants
#define HIDDEN 1024
#define NHEADS 16
#define HD     64
#define BATCH  4
#define SEQ    4096
#define MTOT   (BATCH*SEQ)   // 16384
#define EPSF   1e-3f

typedef unsigned short u16;
typedef unsigned int   u32;
typedef __bf16 bf16x8 __attribute__((ext_vector_type(8)));
typedef u16    u16x8  __attribute__((ext_vector_type(8)));
typedef float  f32x4  __attribute__((ext_vector_type(4)));
typedef u32    u32x4  __attribute__((ext_vector_type(4)));

// f32 -> bf16 (RNE) via the compiler-native scalar __bf16 type.
__device__ inline u16 f2bf(float a) {
    __bf16 h = (__bf16)a;
    return __builtin_bit_cast(u16, h);
}
__device__ inline u32 pack2bf(float a, float b) {
    return (u32)f2bf(a) | ((u32)f2bf(b) << 16);
}
__device__ inline float bf2f(u16 x) {
    return __builtin_bit_cast(float, (u32)x << 16);
}
__device__ inline f32x4 mfma16(bf16x8 a, bf16x8 b, f32x4 c) {
    return __builtin_amdgcn_mfma_f32_16x16x32_bf16(a, b, c, 0, 0, 0);
}
// async global->LDS, 16B per lane; lptr wave-uniform; HW writes lptr+lane*16
// (linear). Swizzle lives in the per-lane GLOBAL address (rule #21).
__device__ inline void gl_lds16(const void* g, void* l) {
    __builtin_amdgcn_global_load_lds(
        (const __attribute__((address_space(1))) void*)g,
        (__attribute__((address_space(3))) void*)l,
        16, 0, 0);
}

// ---------------------------------------------------------------------------
// Kernel 1: weight transpose+convert (Wt[c][d] bf16 = W[d][c] f32), plus
// zeroing of the kvsT/ks_sum accumulator region (ws is poisoned each launch).
// grid (16,16,4), 256 threads. z<3: one 64x64 transpose tile; z==3: zero.
// ---------------------------------------------------------------------------
__global__ __launch_bounds__(256) void prep_kernel(
    const float* __restrict__ W0, const float* __restrict__ W1,
    const float* __restrict__ W2, u16* __restrict__ Wt,
    float* __restrict__ zero_base)
{
    const int t = threadIdx.x;
    if (blockIdx.z == 3) {
        const int base = (blockIdx.y * 16 + blockIdx.x) * 256 + t;
        const int total = 64*64*64 + 64*64;   // kvsT + ks_sum floats (contiguous)
        for (int idx = base; idx < total; idx += 65536) zero_base[idx] = 0.f;
        return;
    }
    const int z = blockIdx.z;
    const float* __restrict__ W = (z == 0) ? W0 : ((z == 1) ? W1 : W2);
    u16* __restrict__ Wz = Wt + (size_t)z * HIDDEN * HIDDEN;
    const int d0 = blockIdx.y * 64, c0 = blockIdx.x * 64;
    __shared__ u16 T[64 * 72];   // row stride 72 u16 to break bank alignment
    {
        const int r = t & 63, p = t >> 6;   // row d, 16-col part
        const float* src = W + (size_t)(d0 + r) * HIDDEN + c0 + p * 16;
        f32x4 x0 = *(const f32x4*)src,       x1 = *(const f32x4*)(src + 4);
        f32x4 x2 = *(const f32x4*)(src + 8), x3 = *(const f32x4*)(src + 12);
        u32x4 y0 = { pack2bf(x0[0],x0[1]), pack2bf(x0[2],x0[3]),
                     pack2bf(x1[0],x1[1]), pack2bf(x1[2],x1[3]) };
        u32x4 y1 = { pack2bf(x2[0],x2[1]), pack2bf(x2[2],x2[3]),
                     pack2bf(x3[0],x3[1]), pack2bf(x3[2],x3[3]) };
        *(u32x4*)((char*)T + (size_t)(r * 72 + p * 16) * 2)     = y0;
        *(u32x4*)((char*)T + (size_t)(r * 72 + p * 16 + 8) * 2) = y1;
    }
    __syncthreads();
    {
        const int c = t & 63, p = t >> 6;   // out row c, 16-d part
        u16 vals[16];
        #pragma unroll
        for (int i = 0; i < 16; ++i) vals[i] = T[(p * 16 + i) * 72 + c];
        u16* dst = Wz + (size_t)(c0 + c) * HIDDEN + d0 + p * 16;
        *(u16x8*)dst       = *(const u16x8*)&vals[0];
        *(u16x8*)(dst + 8) = *(const u16x8*)&vals[8];
    }
}

// ---------------------------------------------------------------------------
// Kernel 2: projection GEMM with FUSED f32->bf16 on the A-path.
// P_z[16384][1024] bf16 = act(X_z f32 @ W_z). 128x128 tile, BK=64, 4 waves,
// 4x4 16x16x32 frags/wave, grid (8,128,3).
//   A: reg-staged (global f32x4 pair -> cvt -> swizzled ds_write_b128),
//      next K-tile's loads issued under the MFMA phase (T14 split).
//   B: global_load_lds 16B/lane, linear LDS dest, source pre-swizzled.
// LDS layout (both tiles): physical slot s of row r holds chunk s^(r&7);
// all ds_reads apply the same XOR => conflict-free b128 fragment reads.
// XCD-aware bijective remap (nwg=1024 per z).
// ---------------------------------------------------------------------------
__global__ __launch_bounds__(256) void gemm_proj(
    const float* __restrict__ X0, const float* __restrict__ X1,
    const float* __restrict__ X2, const u16* __restrict__ Wt,
    u16* __restrict__ P)
{
    const int z = blockIdx.z;
    const float* __restrict__ X = (z == 0) ? X0 : ((z == 1) ? X1 : X2);
    const u16* __restrict__ W = Wt + (size_t)z * HIDDEN * HIDDEN;
    u16* __restrict__ Pz = P + (size_t)z * ((size_t)MTOT * HIDDEN);
    const int doact = (z < 2);

    const int lin = blockIdx.y * 8 + blockIdx.x;      // 0..1023
    const int swz = (lin & 7) * 128 + (lin >> 3);     // bijective XCD remap
    const int m0 = (swz >> 3) * 128;
    const int n0 = (swz & 7) * 128;

    __shared__ u16 As[128 * 64];   // [row][slot] of 8 bf16
    __shared__ u16 Bs[128 * 64];

    const int t = threadIdx.x, lane = t & 63, wid = t >> 6;
    const int wr = (wid >> 1) * 64, wc = (wid & 1) * 64;
    const int l15 = lane & 15, l4 = lane >> 4;
    // A staging (reg): thread covers rows (t>>3)+32i, chunk t&7
    const int arow = t >> 3, acol = t & 7;
    // B staging (gl_lds16): lane covers row rbase+(lane>>3), slot lane&7
    const int brow = lane >> 3;
    const int bchunk = (lane & 7) ^ brow;        // pre-swizzled source chunk

    f32x4 acc[4][4];
    #pragma unroll
    for (int i = 0; i < 4; ++i)
        #pragma unroll
        for (int j = 0; j < 4; ++j) acc[i][j] = f32x4{0.f, 0.f, 0.f, 0.f};

    // prologue: A regs for kt=0
    f32x4 a0[4], a1[4];
    #pragma unroll
    for (int i = 0; i < 4; ++i) {
        const float* ap = X + (size_t)(m0 + arow + 32 * i) * HIDDEN + acol * 8;
        a0[i] = *(const f32x4*)ap;
        a1[i] = *(const f32x4*)(ap + 4);
    }

    for (int kt = 0; kt < HIDDEN / 64; ++kt) {
        const int k0 = kt * 64;
        __syncthreads();   // all waves done reading LDS before overwrite
        #pragma unroll
        for (int i = 0; i < 4; ++i) {
            const int r = arow + 32 * i;
            const int cd = acol ^ (r & 7);
            u32x4 apk = { pack2bf(a0[i][0], a0[i][1]), pack2bf(a0[i][2], a0[i][3]),
                          pack2bf(a1[i][0], a1[i][1]), pack2bf(a1[i][2], a1[i][3]) };
            *(u32x4*)((char*)As + (size_t)r * 128 + cd * 16) = apk;
        }
        #pragma unroll
        for (int g = 0; g < 4; ++g) {
            const int rbase = wid * 32 + g * 8;
            gl_lds16(W + (size_t)(n0 + rbase + brow) * HIDDEN + k0 + bchunk * 8,
                     &Bs[rbase * 64]);
        }
        // T14: issue NEXT K-tile's A loads now; latency hides under MFMA.
        if (kt + 1 < HIDDEN / 64) {
            #pragma unroll
            for (int i = 0; i < 4; ++i) {
                const float* ap = X + (size_t)(m0 + arow + 32 * i) * HIDDEN
                                    + (k0 + 64) + acol * 8;
                a0[i] = *(const f32x4*)ap;
                a1[i] = *(const f32x4*)(ap + 4);
            }
        }
        __syncthreads();   // drains lgkm (ds_write) + vmcnt (gl_lds B)
        #pragma unroll
        for (int ks = 0; ks < 2; ++ks) {
            bf16x8 af[4], bfr[4];
            #pragma unroll
            for (int mi = 0; mi < 4; ++mi) {
                const int r = wr + mi * 16 + l15;
                const int c = (ks * 4 + l4) ^ (r & 7);
                af[mi] = *(const bf16x8*)((const char*)As + (size_t)r * 128 + c * 16);
            }
            #pragma unroll
            for (int ni = 0; ni < 4; ++ni) {
                const int r = wc + ni * 16 + l15;
                const int c = (ks * 4 + l4) ^ (r & 7);
                bfr[ni] = *(const bf16x8*)((const char*)Bs + (size_t)r * 128 + c * 16);
            }
            #pragma unroll
            for (int mi = 0; mi < 4; ++mi)
                #pragma unroll
                for (int ni = 0; ni < 4; ++ni)
                    acc[mi][ni] = mfma16(af[mi], bfr[ni], acc[mi][ni]);
        }
    }
    #pragma unroll
    for (int mi = 0; mi < 4; ++mi) {
        #pragma unroll
        for (int ni = 0; ni < 4; ++ni) {
            const int mrow = m0 + wr + mi * 16 + l4 * 4;   // C row = 4*(l>>4)+reg
            const int ncol = n0 + wc + ni * 16 + l15;      // C col = lane&15
            #pragma unroll
            for (int r = 0; r < 4; ++r) {
                float v = acc[mi][ni][r];
                if (doact) v = fmaxf(v, 0.f) + EPSF;      // relu + eps (q,k)
                Pz[(size_t)(mrow + r) * HIDDEN + ncol] = f2bf(v);
            }
        }
    }
}

// ---------------------------------------------------------------------------
// Kernel 3: kvsT[bn][d][m] += sum_s k'[s,m]*v'[s,d]; ks_sum[bn][m] += sum_s k'.
// Vector outer-product in fp32, atomics across 16 s-chunks. grid (64,16).
// ---------------------------------------------------------------------------
__global__ __launch_bounds__(256) void kvs_kernel(
    const u16* __restrict__ Kp, const u16* __restrict__ Vp,
    float* __restrict__ kvsT, float* __restrict__ ks_sum)
{
    const int bn = blockIdx.x, sc = blockIdx.y;
    const int b = bn >> 4, n = bn & 15;
    __shared__ float Ks[64 * 64];
    __shared__ float Vs[64 * 64];
    const int t = threadIdx.x;
    const int tm = t & 15, td = t >> 4;
    float acc[4][4] = {};
    float ksa[4] = {0.f, 0.f, 0.f, 0.f};
    const size_t rowbase = ((size_t)b * SEQ + (size_t)sc * 256) * HIDDEN + n * 64;

    for (int st = 0; st < 4; ++st) {
        __syncthreads();
        #pragma unroll
        for (int i = 0; i < 2; ++i) {
            const int j = i * 256 + t;
            const int r = j >> 3, c = j & 7;
            const size_t off = rowbase + (size_t)(st * 64 + r) * HIDDEN + c * 8;
            u16x8 kk = *(const u16x8*)(Kp + off);
            u16x8 vv = *(const u16x8*)(Vp + off);
            f32x4 ka{bf2f(kk[0]), bf2f(kk[1]), bf2f(kk[2]), bf2f(kk[3])};
            f32x4 kb{bf2f(kk[4]), bf2f(kk[5]), bf2f(kk[6]), bf2f(kk[7])};
            f32x4 va{bf2f(vv[0]), bf2f(vv[1]), bf2f(vv[2]), bf2f(vv[3])};
            f32x4 vb{bf2f(vv[4]), bf2f(vv[5]), bf2f(vv[6]), bf2f(vv[7])};
            *(f32x4*)&Ks[r * 64 + c * 8]     = ka;
            *(f32x4*)&Ks[r * 64 + c * 8 + 4] = kb;
            *(f32x4*)&Vs[r * 64 + c * 8]     = va;
            *(f32x4*)&Vs[r * 64 + c * 8 + 4] = vb;
        }
        __syncthreads();
        for (int s = 0; s < 64; ++s) {
            const f32x4 kk = *(const f32x4*)&Ks[s * 64 + tm * 4];
            const f32x4 vv = *(const f32x4*)&Vs[s * 64 + td * 4];
            #pragma unroll
            for (int i = 0; i < 4; ++i) {
                ksa[i] += kk[i];
                #pragma unroll
                for (int j = 0; j < 4; ++j) acc[i][j] += kk[i] * vv[j];
            }
        }
    }
    float* kt_bn = kvsT + (size_t)bn * 64 * 64;
    #pragma unroll
    for (int j = 0; j < 4; ++j)
        #pragma unroll
        for (int i = 0; i < 4; ++i)
            atomicAdd(&kt_bn[(td * 4 + j) * 64 + tm * 4 + i], acc[i][j]);
    if (td == 0) {   // ksa identical across td for a given tm -> add once
        #pragma unroll
        for (int i = 0; i < 4; ++i)
            atomicAdd(&ks_sum[bn * 64 + tm * 4 + i], ksa[i]);
    }
}

// ---------------------------------------------------------------------------
// Kernel 4: out[b][s][n*64+d] = (q' @ kvs) / (q' . ks_sum). MFMA over m (=64).
// grid (64,16): (b,n) x 256-row s-chunk.
// ---------------------------------------------------------------------------
__global__ __launch_bounds__(256) void out_kernel(
    const u16* __restrict__ Qp, const float* __restrict__ kvsT,
    const float* __restrict__ ks_sum, float* __restrict__ out)
{
    const int bn = blockIdx.x, sc = blockIdx.y;
    const int b = bn >> 4, n = bn & 15;
    __shared__ u16 Aq[256 * 64];
    __shared__ u16 Bk[64 * 64];
    __shared__ float ksl[64];
    __shared__ float nrm[256];
    const int t = threadIdx.x, lane = t & 63, wid = t >> 6;
    const int l15 = lane & 15, l4 = lane >> 4;
    const size_t qbase = ((size_t)b * SEQ + (size_t)sc * 256) * HIDDEN + n * 64;

    #pragma unroll
    for (int i = 0; i < 8; ++i) {
        const int j = i * 256 + t;
        const int r = j >> 3, c = j & 7;
        u16x8 q8 = *(const u16x8*)(Qp + qbase + (size_t)r * HIDDEN + c * 8);
        *(u16x8*)((char*)Aq + (size_t)r * 128 + ((c ^ (r & 7)) * 16)) = q8;
    }
    {
        const int d = t & 63, p = t >> 6;
        const float* src = kvsT + ((size_t)bn * 64 + d) * 64 + p * 16;
        f32x4 x0 = *(const f32x4*)src,        x1 = *(const f32x4*)(src + 4);
        f32x4 x2 = *(const f32x4*)(src + 8),  x3 = *(const f32x4*)(src + 12);
        u32x4 y0 = { pack2bf(x0[0],x0[1]), pack2bf(x0[2],x0[3]),
                     pack2bf(x1[0],x1[1]), pack2bf(x1[2],x1[3]) };
        u32x4 y1 = { pack2bf(x2[0],x2[1]), pack2bf(x2[2],x2[3]),
                     pack2bf(x3[0],x3[1]), pack2bf(x3[2],x3[3]) };
        *(u32x4*)((char*)Bk + (size_t)d * 128 + (((p * 2)     ^ (d & 7)) * 16)) = y0;
        *(u32x4*)((char*)Bk + (size_t)d * 128 + (((p * 2 + 1) ^ (d & 7)) * 16)) = y1;
    }
    if (t < 16) ((f32x4*)ksl)[t] = ((const f32x4*)(ks_sum + bn * 64))[t];
    __syncthreads();
    {   // normalizer for this thread's s-row (row t), fp32
        float s = 0.f;
        #pragma unroll
        for (int c = 0; c < 8; ++c) {
            u16x8 q8 = *(const u16x8*)((const char*)Aq + (size_t)t * 128 + ((c ^ (t & 7)) * 16));
            #pragma unroll
            for (int e = 0; e < 8; ++e) s += bf2f(q8[e]) * ksl[c * 8 + e];
        }
        nrm[t] = s;   // strictly positive: q' >= eps, ks_sum >= 4096*eps
    }
    __syncthreads();
    f32x4 acc[4][4];
    #pragma unroll
    for (int i = 0; i < 4; ++i)
        #pragma unroll
        for (int j = 0; j < 4; ++j) acc[i][j] = f32x4{0.f, 0.f, 0.f, 0.f};
    #pragma unroll
    for (int ks = 0; ks < 2; ++ks) {
        bf16x8 af[4], bfr[4];
        #pragma unroll
        for (int mi = 0; mi < 4; ++mi) {
            const int r = wid * 64 + mi * 16 + l15;
            const int c = (ks * 4 + l4) ^ (r & 7);
            af[mi] = *(const bf16x8*)((const char*)Aq + (size_t)r * 128 + c * 16);
        }
        #pragma unroll
        for (int ni = 0; ni < 4; ++ni) {
            const int rd = ni * 16 + l15;
            const int c = (ks * 4 + l4) ^ (rd & 7);
            bfr[ni] = *(const bf16x8*)((const char*)Bk + (size_t)rd * 128 + c * 16);
        }
        #pragma unroll
        for (int mi = 0; mi < 4; ++mi)
            #pragma unroll
            for (int ni = 0; ni < 4; ++ni)
                acc[mi][ni] = mfma16(af[mi], bfr[ni], acc[mi][ni]);
    }
    const size_t obase = (size_t)b * SEQ + (size_t)sc * 256;
    #pragma unroll
    for (int mi = 0; mi < 4; ++mi) {
        const int s0l = wid * 64 + mi * 16 + l4 * 4;
        const float rn0 = 1.f / nrm[s0l],     rn1 = 1.f / nrm[s0l + 1];
        const float rn2 = 1.f / nrm[s0l + 2], rn3 = 1.f / nrm[s0l + 3];
        #pragma unroll
        for (int ni = 0; ni < 4; ++ni) {
            const int d = ni * 16 + l15;
            float* op = out + (obase + s0l) * (size_t)HIDDEN + n * 64 + d;
            op[0 * HIDDEN] = acc[mi][ni][0] * rn0;
            op[1 * HIDDEN] = acc[mi][ni][1] * rn1;
            op[2 * HIDDEN] = acc[mi][ni][2] * rn2;
            op[3 * HIDDEN] = acc[mi][ni][3] * rn3;
        }
    }
}

// ---------------------------------------------------------------------------
// ws layout (bytes) — conv pass removed; fixed P buffers, ~108 MB:
//   [0)       Wt bf16 [3][1024][1024]     6,291,456
//   Pq        bf16 [16384][1024]         33,554,432
//   Pk        bf16 [16384][1024]         33,554,432
//   Pv        bf16 [16384][1024]         33,554,432
//   kvsT      f32 [64][64][64]            1,048,576
//   ks_sum    f32 [64][64]                   16,384
// total = 108,019,712
// ---------------------------------------------------------------------------
extern "C" void kernel_launch(void* const* d_in, const int* in_sizes, int n_in,
                              void* d_out, int out_size, void* d_ws, size_t ws_size,
                              hipStream_t stream)
{
    const float* Xq = (const float*)d_in[0];
    const float* Xk = (const float*)d_in[1];
    const float* Xv = (const float*)d_in[2];
    const float* Wq = (const float*)d_in[3];
    const float* Wk = (const float*)d_in[4];
    const float* Wv = (const float*)d_in[5];
    float* out = (float*)d_out;

    char* w = (char*)d_ws;
    u16*   Wt   = (u16*)w;
    u16*   P    = (u16*)(w + 6291456);                  // Pq, Pk, Pv (z-major)
    u16*   Pq   = P;
    u16*   Pk   = P + (size_t)MTOT * HIDDEN;
    u16*   Pv   = P + 2 * (size_t)MTOT * HIDDEN;
    float* kvsT = (float*)(w + 6291456 + 3 * 33554432);
    float* ks   = (float*)(w + 6291456 + 3 * 33554432 + 1048576);

    prep_kernel<<<dim3(16, 16, 4), 256, 0, stream>>>(Wq, Wk, Wv, Wt, kvsT);
    gemm_proj<<<dim3(8, 128, 3), 256, 0, stream>>>(Xq, Xk, Xv, Wt, P);
    kvs_kernel<<<dim3(64, 16), 256, 0, stream>>>(Pk, Pv, kvsT, ks);
    out_kernel<<<dim3(64, 16), 256, 0, stream>>>(Pq, kvsT, ks, out);
}

// Round 11
// 442.621 us; speedup vs baseline: 1.0758x; 1.0509x over previous
//
#include <hip/hip_runtime.h>
#include <hip/hip_bf16.h>
#include <cstdint>
#include <cstddef>

// Problem constants
#define HIDDEN 1024
#define NHEADS 16
#define HD     64
#define BATCH  4
#define SEQ    4096
#define MTOT   (BATCH*SEQ)   // 16384
#define EPSF   1e-3f

typedef unsigned short u16;
typedef unsigned int   u32;
typedef __bf16 bf16x8 __attribute__((ext_vector_type(8)));
typedef u16    u16x8  __attribute__((ext_vector_type(8)));
typedef float  f32x4  __attribute__((ext_vector_type(4)));
typedef u32    u32x4  __attribute__((ext_vector_type(4)));

// f32 -> bf16 (RNE) via the compiler-native scalar __bf16 type.
__device__ inline u16 f2bf(float a) {
    __bf16 h = (__bf16)a;
    return __builtin_bit_cast(u16, h);
}
__device__ inline u32 pack2bf(float a, float b) {
    return (u32)f2bf(a) | ((u32)f2bf(b) << 16);
}
__device__ inline float bf2f(u16 x) {
    return __builtin_bit_cast(float, (u32)x << 16);
}
__device__ inline f32x4 mfma16(bf16x8 a, bf16x8 b, f32x4 c) {
    return __builtin_amdgcn_mfma_f32_16x16x32_bf16(a, b, c, 0, 0, 0);
}
// async global->LDS, 16B per lane; lptr wave-uniform; HW writes lptr+lane*16
// (linear). Swizzle lives in the per-lane GLOBAL address (rule #21).
__device__ inline void gl_lds16(const void* g, void* l) {
    __builtin_amdgcn_global_load_lds(
        (const __attribute__((address_space(1))) void*)g,
        (__attribute__((address_space(3))) void*)l,
        16, 0, 0);
}

// ---------------------------------------------------------------------------
// Kernel 1: weight transpose+convert (Wt[c][d] bf16 = W[d][c] f32), plus
// zeroing of the kvsT/ks_sum accumulator region (ws is poisoned each launch).
// grid (16,16,4), 256 threads. z<3: one 64x64 transpose tile; z==3: zero.
// ---------------------------------------------------------------------------
__global__ __launch_bounds__(256) void prep_kernel(
    const float* __restrict__ W0, const float* __restrict__ W1,
    const float* __restrict__ W2, u16* __restrict__ Wt,
    float* __restrict__ zero_base)
{
    const int t = threadIdx.x;
    if (blockIdx.z == 3) {
        const int base = (blockIdx.y * 16 + blockIdx.x) * 256 + t;
        const int total = 64*64*64 + 64*64;   // kvsT + ks_sum floats (contiguous)
        for (int idx = base; idx < total; idx += 65536) zero_base[idx] = 0.f;
        return;
    }
    const int z = blockIdx.z;
    const float* __restrict__ W = (z == 0) ? W0 : ((z == 1) ? W1 : W2);
    u16* __restrict__ Wz = Wt + (size_t)z * HIDDEN * HIDDEN;
    const int d0 = blockIdx.y * 64, c0 = blockIdx.x * 64;
    __shared__ u16 T[64 * 72];   // row stride 72 u16 to break bank alignment
    {
        const int r = t & 63, p = t >> 6;   // row d, 16-col part
        const float* src = W + (size_t)(d0 + r) * HIDDEN + c0 + p * 16;
        f32x4 x0 = *(const f32x4*)src,       x1 = *(const f32x4*)(src + 4);
        f32x4 x2 = *(const f32x4*)(src + 8), x3 = *(const f32x4*)(src + 12);
        u32x4 y0 = { pack2bf(x0[0],x0[1]), pack2bf(x0[2],x0[3]),
                     pack2bf(x1[0],x1[1]), pack2bf(x1[2],x1[3]) };
        u32x4 y1 = { pack2bf(x2[0],x2[1]), pack2bf(x2[2],x2[3]),
                     pack2bf(x3[0],x3[1]), pack2bf(x3[2],x3[3]) };
        *(u32x4*)((char*)T + (size_t)(r * 72 + p * 16) * 2)     = y0;
        *(u32x4*)((char*)T + (size_t)(r * 72 + p * 16 + 8) * 2) = y1;
    }
    __syncthreads();
    {
        const int c = t & 63, p = t >> 6;   // out row c, 16-d part
        u16 vals[16];
        #pragma unroll
        for (int i = 0; i < 16; ++i) vals[i] = T[(p * 16 + i) * 72 + c];
        u16* dst = Wz + (size_t)(c0 + c) * HIDDEN + d0 + p * 16;
        *(u16x8*)dst       = *(const u16x8*)&vals[0];
        *(u16x8*)(dst + 8) = *(const u16x8*)&vals[8];
    }
}

// ---------------------------------------------------------------------------
// Kernel 2: projection GEMM, fused f32->bf16 A-path, 2-PHASE DOUBLE-BUFFERED
// pipeline (T3-lite). P_z = act(X_z f32 @ W_z). 128x128 tile, BK=64, 4 waves,
// 4x4 16x16x32 frags/wave, grid (8,128,3).
// Per K-iter: {ds_write A(kt+1) from regs; gl_lds B(kt+1); load A-regs(kt+2);
//              MFMA on buf[cur]; ONE barrier}. Loads for tile t+1 are issued
// BEFORE the MFMA on tile t, so the barrier's vmcnt/lgkm drain lands after
// ~a full MFMA phase of cover (fixes round-8's serial-drain regression).
// LDS 64KB (2 buf x (As+Bs)); same 2 blocks/CU residency as round-8.
// Swizzle: physical slot s of row r holds chunk s^(r&7) on both paths.
// ---------------------------------------------------------------------------
__global__ __launch_bounds__(256) void gemm_proj(
    const float* __restrict__ X0, const float* __restrict__ X1,
    const float* __restrict__ X2, const u16* __restrict__ Wt,
    u16* __restrict__ P)
{
    const int z = blockIdx.z;
    const float* __restrict__ X = (z == 0) ? X0 : ((z == 1) ? X1 : X2);
    const u16* __restrict__ W = Wt + (size_t)z * HIDDEN * HIDDEN;
    u16* __restrict__ Pz = P + (size_t)z * ((size_t)MTOT * HIDDEN);
    const int doact = (z < 2);

    const int lin = blockIdx.y * 8 + blockIdx.x;      // 0..1023
    const int swz = (lin & 7) * 128 + (lin >> 3);     // bijective XCD remap
    const int m0 = (swz >> 3) * 128;
    const int n0 = (swz & 7) * 128;

    __shared__ u16 As[2][128 * 64];   // [buf][row][slot] of 8 bf16
    __shared__ u16 Bs[2][128 * 64];

    const int t = threadIdx.x, lane = t & 63, wid = t >> 6;
    const int wr = (wid >> 1) * 64, wc = (wid & 1) * 64;
    const int l15 = lane & 15, l4 = lane >> 4;
    const int arow = t >> 3, acol = t & 7;       // A reg-staging coords
    const int brow = lane >> 3;                  // B gl_lds row-in-group
    const int bchunk = (lane & 7) ^ brow;        // pre-swizzled source chunk

    f32x4 acc[4][4];
    #pragma unroll
    for (int i = 0; i < 4; ++i)
        #pragma unroll
        for (int j = 0; j < 4; ++j) acc[i][j] = f32x4{0.f, 0.f, 0.f, 0.f};

    f32x4 a0[4], a1[4];   // A reg relay (holds tile kt+1 during iter kt)

#define LOAD_A(KT)                                                           \
    {                                                                        \
        _Pragma("unroll")                                                    \
        for (int i = 0; i < 4; ++i) {                                        \
            const float* ap = X + (size_t)(m0 + arow + 32 * i) * HIDDEN      \
                                + (KT) * 64 + acol * 8;                      \
            a0[i] = *(const f32x4*)ap;                                       \
            a1[i] = *(const f32x4*)(ap + 4);                                 \
        }                                                                    \
    }
#define WRITE_A(BUF)                                                         \
    {                                                                        \
        _Pragma("unroll")                                                    \
        for (int i = 0; i < 4; ++i) {                                        \
            const int r = arow + 32 * i;                                     \
            const int cd = acol ^ (r & 7);                                   \
            u32x4 apk = { pack2bf(a0[i][0], a0[i][1]),                       \
                          pack2bf(a0[i][2], a0[i][3]),                       \
                          pack2bf(a1[i][0], a1[i][1]),                       \
                          pack2bf(a1[i][2], a1[i][3]) };                     \
            *(u32x4*)((char*)As[BUF] + (size_t)r * 128 + cd * 16) = apk;     \
        }                                                                    \
    }
#define STAGE_B(BUF, KT)                                                     \
    {                                                                        \
        _Pragma("unroll")                                                    \
        for (int g = 0; g < 4; ++g) {                                        \
            const int rbase = wid * 32 + g * 8;                              \
            gl_lds16(W + (size_t)(n0 + rbase + brow) * HIDDEN                \
                       + (KT) * 64 + bchunk * 8,                             \
                     &Bs[BUF][rbase * 64]);                                  \
        }                                                                    \
    }

    // prologue: fill buf0 with tile 0; preload regs for tile 1
    LOAD_A(0);
    WRITE_A(0);
    STAGE_B(0, 0);
    LOAD_A(1);
    __syncthreads();   // buf0 ready (compiler drains vmcnt+lgkm)

    for (int kt = 0; kt < 16; ++kt) {
        const int cur = kt & 1;
        if (kt + 1 < 16) {          // stage NEXT tile into the other buffer
            WRITE_A(cur ^ 1);       // regs hold tile kt+1
            STAGE_B(cur ^ 1, kt + 1);
        }
        if (kt + 2 < 16) LOAD_A(kt + 2);   // relay: regs now hold tile kt+2
        // compute on buf[cur]
        #pragma unroll
        for (int ks = 0; ks < 2; ++ks) {
            bf16x8 af[4], bfr[4];
            #pragma unroll
            for (int mi = 0; mi < 4; ++mi) {
                const int r = wr + mi * 16 + l15;
                const int c = (ks * 4 + l4) ^ (r & 7);
                af[mi] = *(const bf16x8*)((const char*)As[cur] + (size_t)r * 128 + c * 16);
            }
            #pragma unroll
            for (int ni = 0; ni < 4; ++ni) {
                const int r = wc + ni * 16 + l15;
                const int c = (ks * 4 + l4) ^ (r & 7);
                bfr[ni] = *(const bf16x8*)((const char*)Bs[cur] + (size_t)r * 128 + c * 16);
            }
            #pragma unroll
            for (int mi = 0; mi < 4; ++mi)
                #pragma unroll
                for (int ni = 0; ni < 4; ++ni)
                    acc[mi][ni] = mfma16(af[mi], bfr[ni], acc[mi][ni]);
        }
        __syncthreads();   // one barrier per tile: next buffer ready
    }
#undef LOAD_A
#undef WRITE_A
#undef STAGE_B

    #pragma unroll
    for (int mi = 0; mi < 4; ++mi) {
        #pragma unroll
        for (int ni = 0; ni < 4; ++ni) {
            const int mrow = m0 + wr + mi * 16 + l4 * 4;   // C row = 4*(l>>4)+reg
            const int ncol = n0 + wc + ni * 16 + l15;      // C col = lane&15
            #pragma unroll
            for (int r = 0; r < 4; ++r) {
                float v = acc[mi][ni][r];
                if (doact) v = fmaxf(v, 0.f) + EPSF;      // relu + eps (q,k)
                Pz[(size_t)(mrow + r) * HIDDEN + ncol] = f2bf(v);
            }
        }
    }
}

// ---------------------------------------------------------------------------
// Kernel 3: kvsT[bn][d][m] += sum_s k'[s,m]*v'[s,d]; ks_sum[bn][m] += sum_s k'.
// Vector outer-product in fp32. grid (64,8): 512-row s-chunks (halved atomic
// traffic vs round-8's 16 chunks; streaming traffic unchanged at 128 MB).
// ---------------------------------------------------------------------------
__global__ __launch_bounds__(256) void kvs_kernel(
    const u16* __restrict__ Kp, const u16* __restrict__ Vp,
    float* __restrict__ kvsT, float* __restrict__ ks_sum)
{
    const int bn = blockIdx.x, sc = blockIdx.y;
    const int b = bn >> 4, n = bn & 15;
    __shared__ float Ks[64 * 64];
    __shared__ float Vs[64 * 64];
    const int t = threadIdx.x;
    const int tm = t & 15, td = t >> 4;
    float acc[4][4] = {};
    float ksa[4] = {0.f, 0.f, 0.f, 0.f};
    const size_t rowbase = ((size_t)b * SEQ + (size_t)sc * 512) * HIDDEN + n * 64;

    for (int st = 0; st < 8; ++st) {
        __syncthreads();
        #pragma unroll
        for (int i = 0; i < 2; ++i) {
            const int j = i * 256 + t;
            const int r = j >> 3, c = j & 7;
            const size_t off = rowbase + (size_t)(st * 64 + r) * HIDDEN + c * 8;
            u16x8 kk = *(const u16x8*)(Kp + off);
            u16x8 vv = *(const u16x8*)(Vp + off);
            f32x4 ka{bf2f(kk[0]), bf2f(kk[1]), bf2f(kk[2]), bf2f(kk[3])};
            f32x4 kb{bf2f(kk[4]), bf2f(kk[5]), bf2f(kk[6]), bf2f(kk[7])};
            f32x4 va{bf2f(vv[0]), bf2f(vv[1]), bf2f(vv[2]), bf2f(vv[3])};
            f32x4 vb{bf2f(vv[4]), bf2f(vv[5]), bf2f(vv[6]), bf2f(vv[7])};
            *(f32x4*)&Ks[r * 64 + c * 8]     = ka;
            *(f32x4*)&Ks[r * 64 + c * 8 + 4] = kb;
            *(f32x4*)&Vs[r * 64 + c * 8]     = va;
            *(f32x4*)&Vs[r * 64 + c * 8 + 4] = vb;
        }
        __syncthreads();
        for (int s = 0; s < 64; ++s) {
            const f32x4 kk = *(const f32x4*)&Ks[s * 64 + tm * 4];
            const f32x4 vv = *(const f32x4*)&Vs[s * 64 + td * 4];
            #pragma unroll
            for (int i = 0; i < 4; ++i) {
                ksa[i] += kk[i];
                #pragma unroll
                for (int j = 0; j < 4; ++j) acc[i][j] += kk[i] * vv[j];
            }
        }
    }
    float* kt_bn = kvsT + (size_t)bn * 64 * 64;
    #pragma unroll
    for (int j = 0; j < 4; ++j)
        #pragma unroll
        for (int i = 0; i < 4; ++i)
            atomicAdd(&kt_bn[(td * 4 + j) * 64 + tm * 4 + i], acc[i][j]);
    if (td == 0) {   // ksa identical across td for a given tm -> add once
        #pragma unroll
        for (int i = 0; i < 4; ++i)
            atomicAdd(&ks_sum[bn * 64 + tm * 4 + i], ksa[i]);
    }
}

// ---------------------------------------------------------------------------
// Kernel 4: out[b][s][n*64+d] = (q' @ kvs) / (q' . ks_sum). MFMA over m (=64).
// grid (64,16): (b,n) x 256-row s-chunk.
// ---------------------------------------------------------------------------
__global__ __launch_bounds__(256) void out_kernel(
    const u16* __restrict__ Qp, const float* __restrict__ kvsT,
    const float* __restrict__ ks_sum, float* __restrict__ out)
{
    const int bn = blockIdx.x, sc = blockIdx.y;
    const int b = bn >> 4, n = bn & 15;
    __shared__ u16 Aq[256 * 64];
    __shared__ u16 Bk[64 * 64];
    __shared__ float ksl[64];
    __shared__ float nrm[256];
    const int t = threadIdx.x, lane = t & 63, wid = t >> 6;
    const int l15 = lane & 15, l4 = lane >> 4;
    const size_t qbase = ((size_t)b * SEQ + (size_t)sc * 256) * HIDDEN + n * 64;

    #pragma unroll
    for (int i = 0; i < 8; ++i) {
        const int j = i * 256 + t;
        const int r = j >> 3, c = j & 7;
        u16x8 q8 = *(const u16x8*)(Qp + qbase + (size_t)r * HIDDEN + c * 8);
        *(u16x8*)((char*)Aq + (size_t)r * 128 + ((c ^ (r & 7)) * 16)) = q8;
    }
    {
        const int d = t & 63, p = t >> 6;
        const float* src = kvsT + ((size_t)bn * 64 + d) * 64 + p * 16;
        f32x4 x0 = *(const f32x4*)src,        x1 = *(const f32x4*)(src + 4);
        f32x4 x2 = *(const f32x4*)(src + 8),  x3 = *(const f32x4*)(src + 12);
        u32x4 y0 = { pack2bf(x0[0],x0[1]), pack2bf(x0[2],x0[3]),
                     pack2bf(x1[0],x1[1]), pack2bf(x1[2],x1[3]) };
        u32x4 y1 = { pack2bf(x2[0],x2[1]), pack2bf(x2[2],x2[3]),
                     pack2bf(x3[0],x3[1]), pack2bf(x3[2],x3[3]) };
        *(u32x4*)((char*)Bk + (size_t)d * 128 + (((p * 2)     ^ (d & 7)) * 16)) = y0;
        *(u32x4*)((char*)Bk + (size_t)d * 128 + (((p * 2 + 1) ^ (d & 7)) * 16)) = y1;
    }
    if (t < 16) ((f32x4*)ksl)[t] = ((const f32x4*)(ks_sum + bn * 64))[t];
    __syncthreads();
    {   // normalizer for this thread's s-row (row t), fp32
        float s = 0.f;
        #pragma unroll
        for (int c = 0; c < 8; ++c) {
            u16x8 q8 = *(const u16x8*)((const char*)Aq + (size_t)t * 128 + ((c ^ (t & 7)) * 16));
            #pragma unroll
            for (int e = 0; e < 8; ++e) s += bf2f(q8[e]) * ksl[c * 8 + e];
        }
        nrm[t] = s;   // strictly positive: q' >= eps, ks_sum >= 4096*eps
    }
    __syncthreads();
    f32x4 acc[4][4];
    #pragma unroll
    for (int i = 0; i < 4; ++i)
        #pragma unroll
        for (int j = 0; j < 4; ++j) acc[i][j] = f32x4{0.f, 0.f, 0.f, 0.f};
    #pragma unroll
    for (int ks = 0; ks < 2; ++ks) {
        bf16x8 af[4], bfr[4];
        #pragma unroll
        for (int mi = 0; mi < 4; ++mi) {
            const int r = wid * 64 + mi * 16 + l15;
            const int c = (ks * 4 + l4) ^ (r & 7);
            af[mi] = *(const bf16x8*)((const char*)Aq + (size_t)r * 128 + c * 16);
        }
        #pragma unroll
        for (int ni = 0; ni < 4; ++ni) {
            const int rd = ni * 16 + l15;
            const int c = (ks * 4 + l4) ^ (rd & 7);
            bfr[ni] = *(const bf16x8*)((const char*)Bk + (size_t)rd * 128 + c * 16);
        }
        #pragma unroll
        for (int mi = 0; mi < 4; ++mi)
            #pragma unroll
            for (int ni = 0; ni < 4; ++ni)
                acc[mi][ni] = mfma16(af[mi], bfr[ni], acc[mi][ni]);
    }
    const size_t obase = (size_t)b * SEQ + (size_t)sc * 256;
    #pragma unroll
    for (int mi = 0; mi < 4; ++mi) {
        const int s0l = wid * 64 + mi * 16 + l4 * 4;
        const float rn0 = 1.f / nrm[s0l],     rn1 = 1.f / nrm[s0l + 1];
        const float rn2 = 1.f / nrm[s0l + 2], rn3 = 1.f / nrm[s0l + 3];
        #pragma unroll
        for (int ni = 0; ni < 4; ++ni) {
            const int d = ni * 16 + l15;
            float* op = out + (obase + s0l) * (size_t)HIDDEN + n * 64 + d;
            op[0 * HIDDEN] = acc[mi][ni][0] * rn0;
            op[1 * HIDDEN] = acc[mi][ni][1] * rn1;
            op[2 * HIDDEN] = acc[mi][ni][2] * rn2;
            op[3 * HIDDEN] = acc[mi][ni][3] * rn3;
        }
    }
}

// ---------------------------------------------------------------------------
// ws layout (bytes) — ~108 MB:
//   [0)       Wt bf16 [3][1024][1024]     6,291,456
//   Pq        bf16 [16384][1024]         33,554,432
//   Pk        bf16 [16384][1024]         33,554,432
//   Pv        bf16 [16384][1024]         33,554,432
//   kvsT      f32 [64][64][64]            1,048,576
//   ks_sum    f32 [64][64]                   16,384
// total = 108,019,712
// ---------------------------------------------------------------------------
extern "C" void kernel_launch(void* const* d_in, const int* in_sizes, int n_in,
                              void* d_out, int out_size, void* d_ws, size_t ws_size,
                              hipStream_t stream)
{
    const float* Xq = (const float*)d_in[0];
    const float* Xk = (const float*)d_in[1];
    const float* Xv = (const float*)d_in[2];
    const float* Wq = (const float*)d_in[3];
    const float* Wk = (const float*)d_in[4];
    const float* Wv = (const float*)d_in[5];
    float* out = (float*)d_out;

    char* w = (char*)d_ws;
    u16*   Wt   = (u16*)w;
    u16*   P    = (u16*)(w + 6291456);                  // Pq, Pk, Pv (z-major)
    u16*   Pq   = P;
    u16*   Pk   = P + (size_t)MTOT * HIDDEN;
    u16*   Pv   = P + 2 * (size_t)MTOT * HIDDEN;
    float* kvsT = (float*)(w + 6291456 + 3 * 33554432);
    float* ks   = (float*)(w + 6291456 + 3 * 33554432 + 1048576);

    prep_kernel<<<dim3(16, 16, 4), 256, 0, stream>>>(Wq, Wk, Wv, Wt, kvsT);
    gemm_proj<<<dim3(8, 128, 3), 256, 0, stream>>>(Xq, Xk, Xv, Wt, P);
    kvs_kernel<<<dim3(64, 8), 256, 0, stream>>>(Pk, Pv, kvsT, ks);
    out_kernel<<<dim3(64, 16), 256, 0, stream>>>(Pq, kvsT, ks, out);
}